// Round 3
// baseline (29144.351 us; speedup 1.0000x reference)
//
#include <hip/hip_runtime.h>

// AWD-LSTM fused pipeline for MI355X (gfx950).
// B=32, S=1024, E=H=512, 4H=2048. Output fp32 [32,512].
//
// Precision strategy: all matmuls use split-bf16 (hi+lo) operands with
// 3-pass MFMA (hi*hi + hi*lo + lo*hi) into fp32 accumulators -> effectively
// fp32-accurate (rel err ~2^-17). Gates/cell state in fp32.
//
// Structure:
//  1) memset ctr
//  2) k_xpose: x [B][S][E] fp32 -> fragment-ordered split xb (hi/lo) [S][64][32][8]
//  3) k_wsplit x4: w_ih -> row-major split (hi/lo) bf16
//  4) k_rec layer0 (64 WGs, persistent): fused input-GEMM + recurrence,
//     inter-WG h exchange via global hbuf + per-dir atomic counter barrier.
//     Writes x1 (split, fragment-ordered [S][128][32][8]).
//  5) k_rec layer1: same, reads x1, writes hT fp32 [2][32][512]
//  6) k_head: mish(0.5*(hTf+hTb) @ fc_w^T + fc_b)
//
// Workspace ~226 MB (no fp32 pre-activation tensors).

typedef unsigned short u16;
typedef float f32x4 __attribute__((ext_vector_type(4)));
typedef short s16x8 __attribute__((ext_vector_type(8)));

#define MFMA16(a, b, c) __builtin_amdgcn_mfma_f32_16x16x32_bf16((a), (b), (c), 0, 0, 0)

__device__ __forceinline__ u16 f2bf(float f) {
  unsigned u = __float_as_uint(f);
  return (u16)((u + 0x7FFFu + ((u >> 16) & 1u)) >> 16);
}
__device__ __forceinline__ float bf2f(u16 h) {
  return __uint_as_float((unsigned)h << 16);
}

// split 8 fp32 values into hi/lo bf16 packs
__device__ __forceinline__ void split2(const f32x4& a, const f32x4& b, s16x8& hi, s16x8& lo) {
  union { s16x8 v; u16 u[8]; } H, L;
#pragma unroll
  for (int e = 0; e < 4; ++e) {
    u16 h0 = f2bf(a[e]); H.u[e] = h0; L.u[e] = f2bf(a[e] - bf2f(h0));
    u16 h1 = f2bf(b[e]); H.u[e + 4] = h1; L.u[e + 4] = f2bf(b[e] - bf2f(h1));
  }
  hi = H.v; lo = L.v;
}

__device__ __forceinline__ void gload16(const u16* g, u16* l) {
  __builtin_amdgcn_global_load_lds((const __attribute__((address_space(1))) void*)g,
                                   (__attribute__((address_space(3))) void*)l, 16, 0, 0);
}

__device__ __forceinline__ float sigf(float x) {
  return __builtin_amdgcn_rcpf(1.f + __expf(-x));
}
__device__ __forceinline__ float tanh_(float x) {
  float e = __expf(-2.f * fabsf(x));
  float t = (1.f - e) * __builtin_amdgcn_rcpf(1.f + e);
  return copysignf(t, x);
}

// ---------------- prep kernels ----------------

// x [b][s][e] fp32 -> xbhi/xblo fragment order [s][kc=64][m=32][8]
__global__ void k_xpose(const float* __restrict__ x, u16* __restrict__ xbhi,
                        u16* __restrict__ xblo) {
  long g = (long)blockIdx.x * 256 + threadIdx.x;   // [0, 1024*2048)
  int s = (int)(g >> 11);
  int rem = (int)(g & 2047);
  int m = rem >> 6, kc = rem & 63;
  const float* src = x + (long)m * 524288 + (long)s * 512 + kc * 8;
  f32x4 a = *(const f32x4*)src;
  f32x4 b = *(const f32x4*)(src + 4);
  s16x8 hi, lo; split2(a, b, hi, lo);
  long slot = ((long)s * 64 + kc) * 32 + m;
  *(s16x8*)&xbhi[slot * 8] = hi;
  *(s16x8*)&xblo[slot * 8] = lo;
}

// row-major fp32 [n*8] -> hi/lo bf16 same layout
__global__ void k_wsplit(const float* __restrict__ in, u16* __restrict__ ohi,
                         u16* __restrict__ olo) {
  long g = ((long)blockIdx.x * 256 + threadIdx.x) * 8;
  f32x4 a = *(const f32x4*)(in + g);
  f32x4 b = *(const f32x4*)(in + g + 4);
  s16x8 hi, lo; split2(a, b, hi, lo);
  *(s16x8*)&ohi[g] = hi;
  *(s16x8*)&olo[g] = lo;
}

// ---------------- persistent fused LSTM ----------------
// grid = 64 x 256 thr (4 waves). dir = bid>>5, wg = bid&31.
// Wave owns 4 h-cols x 4 gates = 16 gate rows; WG owns 16 h-cols (64 rows).
// Per step: stage x_t split (LDS) -> 3-pass x-MFMA (pre-barrier work) ->
// spin on ctr -> stage h split -> 3-pass h-MFMA (w_hh split in VGPRs) ->
// gates/cell -> write h (hbuf global, fragment order) -> post flag.
__global__ __launch_bounds__(256, 1) void k_rec(
    const u16* __restrict__ xhi, const u16* __restrict__ xlo,  // [S][KC][32][8]
    const u16* __restrict__ wxhiF, const u16* __restrict__ wxloF,
    const u16* __restrict__ wxhiB, const u16* __restrict__ wxloB,  // [2048][K]
    const float* __restrict__ whhF, const float* __restrict__ whhB, // [2048][512]
    const float* __restrict__ mask,   // null unless layer0 (fwd only)
    const float* __restrict__ bihF, const float* __restrict__ bhhF,
    const float* __restrict__ bihB, const float* __restrict__ bhhB,
    u16* __restrict__ x1hi, u16* __restrict__ x1lo,  // null for layer1
    float* __restrict__ hT,                          // null for layer0
    u16* hbuf,          // [dir][par][half][64][32][8] bf16 (128 KB/dir)
    unsigned* ctr, int S, int KC) {
  __shared__ __attribute__((aligned(16))) u16 xls[65536];  // 128 KB stage buffer
  __shared__ __attribute__((aligned(16))) float hstage[32][16];

  int tid = threadIdx.x;
  int dir = blockIdx.x >> 5;
  int wg = blockIdx.x & 31;
  int lane = tid & 63, wave = tid >> 6;
  int c = lane & 15, mrow = lane >> 4, j = c & 3, hi4 = c >> 2;
  int hiL = wave * 4 + hi4;          // 0..15
  int R = j * 512 + wg * 16 + hiL;   // gate row

  const u16* wxhi = dir ? wxhiB : wxhiF;
  const u16* wxlo = dir ? wxloB : wxloF;
  const float* whh = dir ? whhB : whhF;
  const float* msk = dir ? nullptr : mask;
  float bias = (dir ? bihB[R] : bihF[R]) + (dir ? bhhB[R] : bhhF[R]);
  int KX = KC * 8;
  int KT = KC >> 2;           // 32-k chunks in x GEMM
  int xoffL = KC * 32;        // lo-half slot offset in xls

  // ---- preload w_hh split fragments (128 VGPR) ----
  s16x8 whhHi[16], whhLo[16];
#pragma unroll
  for (int kt = 0; kt < 16; ++kt) {
    const float* wp = whh + (long)R * 512 + kt * 32 + mrow * 8;
    f32x4 a = *(const f32x4*)wp;
    f32x4 b = *(const f32x4*)(wp + 4);
    if (msk) {
      const float* mp = msk + (long)R * 512 + kt * 32 + mrow * 8;
      a *= *(const f32x4*)mp;
      b *= *(const f32x4*)(mp + 4);
    }
    split2(a, b, whhHi[kt], whhLo[kt]);
  }

  float cst[2][4] = {};
  u16* hb = hbuf + dir * 65536;
  unsigned* myctr = ctr + dir;
  bool jlo = (j < 2), jodd = (j & 1);

  for (int t = 0; t < S; ++t) {
    int tt = dir ? (S - 1 - t) : t;

    // ---- stage x_t (hi then lo) into LDS ----
    const u16* xsH = xhi + (long)tt * KC * 256;
    const u16* xsL = xlo + (long)tt * KC * 256;
    for (int s0 = tid; s0 < xoffL; s0 += 256) gload16(xsH + (long)s0 * 8, xls + s0 * 8);
    for (int s0 = tid; s0 < xoffL; s0 += 256) gload16(xsL + (long)s0 * 8, xls + (xoffL + s0) * 8);
    __syncthreads();

    // ---- x GEMM: 3-pass split MFMA, w_ih streamed from L2 ----
    f32x4 aHH[2] = {}, aHL[2] = {}, aLH[2] = {};
#pragma unroll 4
    for (int kt = 0; kt < KT; ++kt) {
      long wo = (long)R * KX + kt * 32 + mrow * 8;
      s16x8 bH = *(const s16x8*)(wxhi + wo);
      s16x8 bL = *(const s16x8*)(wxlo + wo);
      int base = (kt * 4 + mrow) * 32 + c;
#pragma unroll
      for (int mt = 0; mt < 2; ++mt) {
        s16x8 aH = *(const s16x8*)&xls[(base + mt * 16) * 8];
        s16x8 aL = *(const s16x8*)&xls[(xoffL + base + mt * 16) * 8];
        aHH[mt] = MFMA16(aH, bH, aHH[mt]);
        aHL[mt] = MFMA16(aH, bL, aHL[mt]);
        aLH[mt] = MFMA16(aL, bH, aLH[mt]);
      }
    }
    __syncthreads();   // x LDS reads done before h overwrites

    // ---- h GEMM (t>0) ----
    if (t > 0) {
      if (tid == 0) {
        unsigned tgt = 32u * (unsigned)t;
        while (__hip_atomic_load(myctr, __ATOMIC_RELAXED, __HIP_MEMORY_SCOPE_AGENT) < tgt) {
          __builtin_amdgcn_s_sleep(1);
        }
      }
      __syncthreads();
      __builtin_amdgcn_fence(__ATOMIC_ACQUIRE, "agent");
      const u16* hsrc = hb + ((t - 1) & 1) * 32768;
      for (int s0 = tid; s0 < 4096; s0 += 256) gload16(hsrc + s0 * 8, xls + s0 * 8);
      __syncthreads();
#pragma unroll
      for (int kt = 0; kt < 16; ++kt) {
        int base = (kt * 4 + mrow) * 32 + c;
#pragma unroll
        for (int mt = 0; mt < 2; ++mt) {
          s16x8 aH = *(const s16x8*)&xls[(base + mt * 16) * 8];
          s16x8 aL = *(const s16x8*)&xls[(2048 + base + mt * 16) * 8];
          aHH[mt] = MFMA16(aH, whhHi[kt], aHH[mt]);
          aHL[mt] = MFMA16(aH, whhLo[kt], aHL[mt]);
          aLH[mt] = MFMA16(aL, whhHi[kt], aLH[mt]);
        }
      }
    }

    // ---- gates + cell ----
#pragma unroll
    for (int mt = 0; mt < 2; ++mt) {
#pragma unroll
      for (int r = 0; r < 4; ++r) {
        float P = aHH[mt][r] + aHL[mt][r] + aLH[mt][r] + bias;
        float v1 = __shfl_xor(P, 1);
        float v2 = __shfl_xor(P, 2);
        float v3 = __shfl_xor(P, 3);
        float ip = jlo ? (jodd ? v1 : P)  : (jodd ? v3 : v2);
        float fp = jlo ? (jodd ? P  : v1) : (jodd ? v2 : v3);
        float gp = jlo ? (jodd ? v3 : v2) : (jodd ? v1 : P);
        float op = jlo ? (jodd ? v2 : v3) : (jodd ? P  : v1);
        float cs = cst[mt][r];
        float cn = sigf(fp) * cs + sigf(ip) * tanh_(gp);
        float hn = sigf(op) * tanh_(cn);
        cst[mt][r] = cn;
        if (j == 0) {
          int m = mt * 16 + mrow * 4 + r;
          hstage[m][hiL] = hn;
          if (hT && t == S - 1)
            hT[dir * 16384 + m * 512 + wg * 16 + hiL] = hn;
        }
      }
    }
    __syncthreads();   // hstage complete

    // ---- h broadcast (split) + x1 output ----
    if (tid < 64) {
      int kk = tid >> 5, m = tid & 31;
      f32x4 a = *(const f32x4*)&hstage[m][kk * 8];
      f32x4 b = *(const f32x4*)&hstage[m][kk * 8 + 4];
      s16x8 hi, lo; split2(a, b, hi, lo);
      u16* dst = hb + (t & 1) * 32768 + ((wg * 2 + kk) * 32 + m) * 8;
      *(s16x8*)dst = hi;
      *(s16x8*)(dst + 16384) = lo;
    } else if (x1hi && tid < 128) {
      int q = tid - 64, b2 = q >> 1, ch = q & 1;
      f32x4 a = *(const f32x4*)&hstage[b2][ch * 8];
      f32x4 b = *(const f32x4*)&hstage[b2][ch * 8 + 4];
      s16x8 hi, lo; split2(a, b, hi, lo);
      long o = (((long)tt * 128 + dir * 64 + wg * 2 + ch) * 32 + b2) * 8;
      *(s16x8*)&x1hi[o] = hi;
      *(s16x8*)&x1lo[o] = lo;
    }
    __syncthreads();   // all stores drained (barrier waits vmcnt)
    if (tid == 0)
      __hip_atomic_fetch_add(myctr, 1u, __ATOMIC_RELEASE, __HIP_MEMORY_SCOPE_AGENT);
  }
}

// ---------------- head: mish(0.5*(hTf+hTb) @ fc_w^T + fc_b) ----------------
__global__ void k_head(const float* __restrict__ hT, const float* __restrict__ fcw,
                       const float* __restrict__ fcb, float* __restrict__ out) {
  __shared__ float hm[512];
  int b = blockIdx.x;
  int tid = threadIdx.x;
  for (int k = tid; k < 512; k += 256)
    hm[k] = 0.5f * (hT[b * 512 + k] + hT[16384 + b * 512 + k]);
  __syncthreads();
  int o = blockIdx.y * 256 + tid;
  float acc = fcb[o];
  const float* wr = fcw + (long)o * 512;
#pragma unroll 4
  for (int k = 0; k < 512; k += 4) {
    f32x4 w = *(const f32x4*)(wr + k);
    acc += w[0] * hm[k] + w[1] * hm[k + 1] + w[2] * hm[k + 2] + w[3] * hm[k + 3];
  }
  float sp = (acc > 20.f) ? acc : log1pf(expf(acc));
  out[b * 512 + o] = acc * tanhf(sp);
}

// ---------------- launch ----------------
extern "C" void kernel_launch(void* const* d_in, const int* in_sizes, int n_in,
                              void* d_out, int out_size, void* d_ws, size_t ws_size,
                              hipStream_t stream) {
  const float* x     = (const float*)d_in[0];
  const float* wihf0 = (const float*)d_in[1];
  const float* whhf0 = (const float*)d_in[2];
  const float* bihf0 = (const float*)d_in[3];
  const float* bhhf0 = (const float*)d_in[4];
  const float* wihb0 = (const float*)d_in[5];
  const float* whhb0 = (const float*)d_in[6];
  const float* bihb0 = (const float*)d_in[7];
  const float* bhhb0 = (const float*)d_in[8];
  const float* wihf1 = (const float*)d_in[9];
  const float* whhf1 = (const float*)d_in[10];
  const float* bihf1 = (const float*)d_in[11];
  const float* bhhf1 = (const float*)d_in[12];
  const float* wihb1 = (const float*)d_in[13];
  const float* whhb1 = (const float*)d_in[14];
  const float* bihb1 = (const float*)d_in[15];
  const float* bhhb1 = (const float*)d_in[16];
  const float* fcw   = (const float*)d_in[17];
  const float* fcb   = (const float*)d_in[18];
  const float* mask  = (const float*)d_in[19];
  float* out = (float*)d_out;
  (void)in_sizes; (void)n_in; (void)out_size; (void)ws_size;

  char* w = (char*)d_ws;
  size_t off = 0;
  auto take = [&](size_t bytes) -> char* {
    char* p = w + off;
    off += (bytes + 255) & ~(size_t)255;
    return p;
  };
  unsigned* ctr = (unsigned*)take(16);
  u16* xbhi = (u16*)take((size_t)1024 * 64 * 256 * 2);   // 33.5 MB
  u16* xblo = (u16*)take((size_t)1024 * 64 * 256 * 2);
  u16* wxhiF0 = (u16*)take((size_t)2048 * 512 * 2);
  u16* wxloF0 = (u16*)take((size_t)2048 * 512 * 2);
  u16* wxhiB0 = (u16*)take((size_t)2048 * 512 * 2);
  u16* wxloB0 = (u16*)take((size_t)2048 * 512 * 2);
  u16* wxhiF1 = (u16*)take((size_t)2048 * 1024 * 2);
  u16* wxloF1 = (u16*)take((size_t)2048 * 1024 * 2);
  u16* wxhiB1 = (u16*)take((size_t)2048 * 1024 * 2);
  u16* wxloB1 = (u16*)take((size_t)2048 * 1024 * 2);
  u16* x1hi = (u16*)take((size_t)1024 * 128 * 256 * 2);  // 67 MB
  u16* x1lo = (u16*)take((size_t)1024 * 128 * 256 * 2);
  u16* hbuf = (u16*)take((size_t)2 * 65536 * 2);         // 256 KB
  float* hT = (float*)take((size_t)2 * 16384 * 4);       // 128 KB

  hipMemsetAsync(ctr, 0, 16, stream);

  k_xpose<<<8192, 256, 0, stream>>>(x, xbhi, xblo);
  k_wsplit<<<512, 256, 0, stream>>>(wihf0, wxhiF0, wxloF0);
  k_wsplit<<<512, 256, 0, stream>>>(wihb0, wxhiB0, wxloB0);
  k_wsplit<<<1024, 256, 0, stream>>>(wihf1, wxhiF1, wxloF1);
  k_wsplit<<<1024, 256, 0, stream>>>(wihb1, wxhiB1, wxloB1);

  // layer 0: fused input GEMM + recurrence
  k_rec<<<64, 256, 0, stream>>>(xbhi, xblo, wxhiF0, wxloF0, wxhiB0, wxloB0,
                                whhf0, whhb0, mask,
                                bihf0, bhhf0, bihb0, bhhb0,
                                x1hi, x1lo, nullptr, hbuf, ctr, 1024, 64);
  // layer 1
  k_rec<<<64, 256, 0, stream>>>(x1hi, x1lo, wxhiF1, wxloF1, wxhiB1, wxloB1,
                                whhf1, whhb1, nullptr,
                                bihf1, bhhf1, bihb1, bhhb1,
                                nullptr, nullptr, hT, hbuf, ctr + 2, 1024, 128);

  k_head<<<dim3(32, 2), 256, 0, stream>>>(hT, fcw, fcb, out);
}

// Round 4
// 20689.517 us; speedup vs baseline: 1.4087x; 1.4087x over previous
//
#include <hip/hip_runtime.h>

// AWD-LSTM fused pipeline for MI355X (gfx950).
// B=32, S=1024, E=H=512, 4H=2048. Output fp32 [32,512].
//
// Precision: split-bf16 (hi+lo) operands, 3-pass MFMA (hi*hi+hi*lo+lo*hi),
// fp32 accumulate -> ~2^-17 rel err (round-3 measured absmax 1.2e-4).
//
// Round-4 change: fence-free inter-WG h exchange. Round 3's
// release-fetch_add + acquire-fence emitted buffer_wbl2/buffer_inv every
// step, nuking L2 (w_ih refetch each step; FETCH_SIZE 1.5GB). Now:
//   h stores  -> global_store_dwordx4 sc0 sc1 (write-through, inline asm)
//   flag post -> explicit s_waitcnt vmcnt(0) + RELAXED agent fetch_add
//   flag poll -> RELAXED agent load (no cache invalidate)
//   h loads   -> global_load_lds aux=SC0|SC1 (0x11) reading coherence point
// L2 stays warm across steps. Layer 0 additionally holds its w_ih slice in
// registers (template WREG) -> zero per-step weight traffic.

typedef unsigned short u16;
typedef float f32x4 __attribute__((ext_vector_type(4)));
typedef short s16x8 __attribute__((ext_vector_type(8)));

#define MFMA16(a, b, c) __builtin_amdgcn_mfma_f32_16x16x32_bf16((a), (b), (c), 0, 0, 0)

__device__ __forceinline__ u16 f2bf(float f) {
  unsigned u = __float_as_uint(f);
  return (u16)((u + 0x7FFFu + ((u >> 16) & 1u)) >> 16);
}
__device__ __forceinline__ float bf2f(u16 h) {
  return __uint_as_float((unsigned)h << 16);
}

__device__ __forceinline__ void split2(const f32x4& a, const f32x4& b, s16x8& hi, s16x8& lo) {
  union { s16x8 v; u16 u[8]; } H, L;
#pragma unroll
  for (int e = 0; e < 4; ++e) {
    u16 h0 = f2bf(a[e]); H.u[e] = h0; L.u[e] = f2bf(a[e] - bf2f(h0));
    u16 h1 = f2bf(b[e]); H.u[e + 4] = h1; L.u[e + 4] = f2bf(b[e] - bf2f(h1));
  }
  hi = H.v; lo = L.v;
}

// normal cached global->LDS (x, weights)
__device__ __forceinline__ void gload16(const u16* g, u16* l) {
  __builtin_amdgcn_global_load_lds((const __attribute__((address_space(1))) void*)g,
                                   (__attribute__((address_space(3))) void*)l, 16, 0, 0);
}
// device-coherent global->LDS (h exchange): aux = SC0(1) | SC1(16)
__device__ __forceinline__ void gload16c(const u16* g, u16* l) {
  __builtin_amdgcn_global_load_lds((const __attribute__((address_space(1))) void*)g,
                                   (__attribute__((address_space(3))) void*)l, 16, 0, 0x11);
}
// device-coherent 16B store (h exchange)
__device__ __forceinline__ void stc16(u16* p, s16x8 v) {
  asm volatile("global_store_dwordx4 %0, %1, off sc0 sc1" :: "v"(p), "v"(v) : "memory");
}

__device__ __forceinline__ float sigf(float x) {
  return __builtin_amdgcn_rcpf(1.f + __expf(-x));
}
__device__ __forceinline__ float tanh_(float x) {
  float e = __expf(-2.f * fabsf(x));
  float t = (1.f - e) * __builtin_amdgcn_rcpf(1.f + e);
  return copysignf(t, x);
}

// ---------------- prep kernels ----------------

// x [b][s][e] fp32 -> xbhi/xblo fragment order [s][kc=64][m=32][8]
__global__ void k_xpose(const float* __restrict__ x, u16* __restrict__ xbhi,
                        u16* __restrict__ xblo) {
  long g = (long)blockIdx.x * 256 + threadIdx.x;   // [0, 1024*2048)
  int s = (int)(g >> 11);
  int rem = (int)(g & 2047);
  int m = rem >> 6, kc = rem & 63;
  const float* src = x + (long)m * 524288 + (long)s * 512 + kc * 8;
  f32x4 a = *(const f32x4*)src;
  f32x4 b = *(const f32x4*)(src + 4);
  s16x8 hi, lo; split2(a, b, hi, lo);
  long slot = ((long)s * 64 + kc) * 32 + m;
  *(s16x8*)&xbhi[slot * 8] = hi;
  *(s16x8*)&xblo[slot * 8] = lo;
}

// row-major fp32 [n*8] -> hi/lo bf16 same layout
__global__ void k_wsplit(const float* __restrict__ in, u16* __restrict__ ohi,
                         u16* __restrict__ olo) {
  long g = ((long)blockIdx.x * 256 + threadIdx.x) * 8;
  f32x4 a = *(const f32x4*)(in + g);
  f32x4 b = *(const f32x4*)(in + g + 4);
  s16x8 hi, lo; split2(a, b, hi, lo);
  *(s16x8*)&ohi[g] = hi;
  *(s16x8*)&olo[g] = lo;
}

// ---------------- persistent fused LSTM ----------------
// grid = 64 x 256 thr (4 waves). dir = bid>>5, wg = bid&31.
// Wave owns 4 h-cols x 4 gates = 16 gate rows; WG owns 16 h-cols (64 rows).
template <int KC, bool WREG>
__global__ __launch_bounds__(256, 1) void k_rec(
    const u16* __restrict__ xhi, const u16* __restrict__ xlo,  // [S][KC][32][8]
    const u16* __restrict__ wxhiF, const u16* __restrict__ wxloF,
    const u16* __restrict__ wxhiB, const u16* __restrict__ wxloB,  // [2048][K]
    const float* __restrict__ whhF, const float* __restrict__ whhB, // [2048][512]
    const float* __restrict__ mask,   // null unless layer0 (fwd only)
    const float* __restrict__ bihF, const float* __restrict__ bhhF,
    const float* __restrict__ bihB, const float* __restrict__ bhhB,
    u16* __restrict__ x1hi, u16* __restrict__ x1lo,  // null for layer1
    float* __restrict__ hT,                          // null for layer0
    u16* hbuf,          // [dir][par][half][64][32][8] bf16
    unsigned* ctr, int S) {
  __shared__ __attribute__((aligned(16))) u16 xls[65536];  // 128 KB stage buffer
  __shared__ __attribute__((aligned(16))) float hstage[32][16];

  constexpr int KT = KC >> 2;       // 32-k chunks in x GEMM
  constexpr int KX = KC * 8;        // K
  constexpr int xoffL = KC * 32;    // lo-half slot offset in xls

  int tid = threadIdx.x;
  int dir = blockIdx.x >> 5;
  int wg = blockIdx.x & 31;
  int lane = tid & 63, wave = tid >> 6;
  int c = lane & 15, mrow = lane >> 4, j = c & 3, hi4 = c >> 2;
  int hiL = wave * 4 + hi4;          // 0..15
  int R = j * 512 + wg * 16 + hiL;   // gate row

  const u16* wxhi = dir ? wxhiB : wxhiF;
  const u16* wxlo = dir ? wxloB : wxloF;
  const float* whh = dir ? whhB : whhF;
  const float* msk = dir ? nullptr : mask;
  float bias = (dir ? bihB[R] : bihF[R]) + (dir ? bhhB[R] : bhhF[R]);

  // ---- preload w_hh split fragments (128 VGPR) ----
  s16x8 whhHi[16], whhLo[16];
#pragma unroll
  for (int kt = 0; kt < 16; ++kt) {
    const float* wp = whh + (long)R * 512 + kt * 32 + mrow * 8;
    f32x4 a = *(const f32x4*)wp;
    f32x4 b = *(const f32x4*)(wp + 4);
    if (msk) {
      const float* mp = msk + (long)R * 512 + kt * 32 + mrow * 8;
      a *= *(const f32x4*)mp;
      b *= *(const f32x4*)(mp + 4);
    }
    split2(a, b, whhHi[kt], whhLo[kt]);
  }

  // ---- layer0: w_ih slice lives in registers too (128 VGPR) ----
  constexpr int NW = WREG ? KT : 1;
  s16x8 wxH[NW], wxL[NW];
  if constexpr (WREG) {
#pragma unroll
    for (int kt = 0; kt < KT; ++kt) {
      long wo = (long)R * KX + kt * 32 + mrow * 8;
      wxH[kt] = *(const s16x8*)(wxhi + wo);
      wxL[kt] = *(const s16x8*)(wxlo + wo);
    }
  }

  float cst[2][4] = {};
  u16* hb = hbuf + dir * 65536;
  unsigned* myctr = ctr + dir;
  bool jlo = (j < 2), jodd = (j & 1);

  for (int t = 0; t < S; ++t) {
    int tt = dir ? (S - 1 - t) : t;

    // ---- stage x_t (hi then lo) into LDS (cached path) ----
    const u16* xsH = xhi + (long)tt * KC * 256;
    const u16* xsL = xlo + (long)tt * KC * 256;
    for (int s0 = tid; s0 < xoffL; s0 += 256) gload16(xsH + (long)s0 * 8, xls + s0 * 8);
    for (int s0 = tid; s0 < xoffL; s0 += 256) gload16(xsL + (long)s0 * 8, xls + (xoffL + s0) * 8);
    __syncthreads();

    // ---- x GEMM: 3-pass split MFMA ----
    f32x4 aHH[2] = {}, aHL[2] = {}, aLH[2] = {};
    if constexpr (WREG) {
#pragma unroll
      for (int kt = 0; kt < KT; ++kt) {
        int base = (kt * 4 + mrow) * 32 + c;
#pragma unroll
        for (int mt = 0; mt < 2; ++mt) {
          s16x8 aH = *(const s16x8*)&xls[(base + mt * 16) * 8];
          s16x8 aL = *(const s16x8*)&xls[(xoffL + base + mt * 16) * 8];
          aHH[mt] = MFMA16(aH, wxH[kt], aHH[mt]);
          aHL[mt] = MFMA16(aH, wxL[kt], aHL[mt]);
          aLH[mt] = MFMA16(aL, wxH[kt], aLH[mt]);
        }
      }
    } else {
#pragma unroll 4
      for (int kt = 0; kt < KT; ++kt) {
        long wo = (long)R * KX + kt * 32 + mrow * 8;
        s16x8 bH = *(const s16x8*)(wxhi + wo);
        s16x8 bL = *(const s16x8*)(wxlo + wo);
        int base = (kt * 4 + mrow) * 32 + c;
#pragma unroll
        for (int mt = 0; mt < 2; ++mt) {
          s16x8 aH = *(const s16x8*)&xls[(base + mt * 16) * 8];
          s16x8 aL = *(const s16x8*)&xls[(xoffL + base + mt * 16) * 8];
          aHH[mt] = MFMA16(aH, bH, aHH[mt]);
          aHL[mt] = MFMA16(aH, bL, aHL[mt]);
          aLH[mt] = MFMA16(aL, bH, aLH[mt]);
        }
      }
    }
    __syncthreads();   // x LDS reads done before h overwrites

    // ---- h GEMM (t>0) ----
    if (t > 0) {
      if (tid == 0) {
        unsigned tgt = 32u * (unsigned)t;
        while (__hip_atomic_load(myctr, __ATOMIC_RELAXED, __HIP_MEMORY_SCOPE_AGENT) < tgt) {
          __builtin_amdgcn_s_sleep(1);
        }
      }
      __syncthreads();
      asm volatile("" ::: "memory");   // no cache maintenance; sc-bit loads below
      const u16* hsrc = hb + ((t - 1) & 1) * 32768;
      for (int s0 = tid; s0 < 4096; s0 += 256) gload16c(hsrc + s0 * 8, xls + s0 * 8);
      __syncthreads();
#pragma unroll
      for (int kt = 0; kt < 16; ++kt) {
        int base = (kt * 4 + mrow) * 32 + c;
#pragma unroll
        for (int mt = 0; mt < 2; ++mt) {
          s16x8 aH = *(const s16x8*)&xls[(base + mt * 16) * 8];
          s16x8 aL = *(const s16x8*)&xls[(2048 + base + mt * 16) * 8];
          aHH[mt] = MFMA16(aH, whhHi[kt], aHH[mt]);
          aHL[mt] = MFMA16(aH, whhLo[kt], aHL[mt]);
          aLH[mt] = MFMA16(aL, whhHi[kt], aLH[mt]);
        }
      }
    }

    // ---- gates + cell ----
#pragma unroll
    for (int mt = 0; mt < 2; ++mt) {
#pragma unroll
      for (int r = 0; r < 4; ++r) {
        float P = aHH[mt][r] + aHL[mt][r] + aLH[mt][r] + bias;
        float v1 = __shfl_xor(P, 1);
        float v2 = __shfl_xor(P, 2);
        float v3 = __shfl_xor(P, 3);
        float ip = jlo ? (jodd ? v1 : P)  : (jodd ? v3 : v2);
        float fp = jlo ? (jodd ? P  : v1) : (jodd ? v2 : v3);
        float gp = jlo ? (jodd ? v3 : v2) : (jodd ? v1 : P);
        float op = jlo ? (jodd ? v2 : v3) : (jodd ? P  : v1);
        float cs = cst[mt][r];
        float cn = sigf(fp) * cs + sigf(ip) * tanh_(gp);
        float hn = sigf(op) * tanh_(cn);
        cst[mt][r] = cn;
        if (j == 0) {
          int m = mt * 16 + mrow * 4 + r;
          hstage[m][hiL] = hn;
          if (hT && t == S - 1)
            hT[dir * 16384 + m * 512 + wg * 16 + hiL] = hn;
        }
      }
    }
    __syncthreads();   // hstage complete

    // ---- h broadcast (split, device-coherent stores) + x1 output ----
    if (tid < 64) {
      int kk = tid >> 5, m = tid & 31;
      f32x4 a = *(const f32x4*)&hstage[m][kk * 8];
      f32x4 b = *(const f32x4*)&hstage[m][kk * 8 + 4];
      s16x8 hi, lo; split2(a, b, hi, lo);
      u16* dst = hb + (t & 1) * 32768 + ((wg * 2 + kk) * 32 + m) * 8;
      stc16(dst, hi);
      stc16(dst + 16384, lo);
    } else if (x1hi && tid < 128) {
      int q = tid - 64, b2 = q >> 1, ch = q & 1;
      f32x4 a = *(const f32x4*)&hstage[b2][ch * 8];
      f32x4 b = *(const f32x4*)&hstage[b2][ch * 8 + 4];
      s16x8 hi, lo; split2(a, b, hi, lo);
      long o = (((long)tt * 128 + dir * 64 + wg * 2 + ch) * 32 + b2) * 8;
      *(s16x8*)&x1hi[o] = hi;
      *(s16x8*)&x1lo[o] = lo;
    }
    __syncthreads();
    if (tid == 0) {
      // wave 0 issued the hb stores; drain them, then post (relaxed: no wbL2)
      asm volatile("s_waitcnt vmcnt(0)" ::: "memory");
      __hip_atomic_fetch_add(myctr, 1u, __ATOMIC_RELAXED, __HIP_MEMORY_SCOPE_AGENT);
    }
  }
}

// ---------------- head: mish(0.5*(hTf+hTb) @ fc_w^T + fc_b) ----------------
__global__ void k_head(const float* __restrict__ hT, const float* __restrict__ fcw,
                       const float* __restrict__ fcb, float* __restrict__ out) {
  __shared__ float hm[512];
  int b = blockIdx.x;
  int tid = threadIdx.x;
  for (int k = tid; k < 512; k += 256)
    hm[k] = 0.5f * (hT[b * 512 + k] + hT[16384 + b * 512 + k]);
  __syncthreads();
  int o = blockIdx.y * 256 + tid;
  float acc = fcb[o];
  const float* wr = fcw + (long)o * 512;
#pragma unroll 4
  for (int k = 0; k < 512; k += 4) {
    f32x4 w = *(const f32x4*)(wr + k);
    acc += w[0] * hm[k] + w[1] * hm[k + 1] + w[2] * hm[k + 2] + w[3] * hm[k + 3];
  }
  float sp = (acc > 20.f) ? acc : log1pf(expf(acc));
  out[b * 512 + o] = acc * tanhf(sp);
}

// ---------------- launch ----------------
extern "C" void kernel_launch(void* const* d_in, const int* in_sizes, int n_in,
                              void* d_out, int out_size, void* d_ws, size_t ws_size,
                              hipStream_t stream) {
  const float* x     = (const float*)d_in[0];
  const float* wihf0 = (const float*)d_in[1];
  const float* whhf0 = (const float*)d_in[2];
  const float* bihf0 = (const float*)d_in[3];
  const float* bhhf0 = (const float*)d_in[4];
  const float* wihb0 = (const float*)d_in[5];
  const float* whhb0 = (const float*)d_in[6];
  const float* bihb0 = (const float*)d_in[7];
  const float* bhhb0 = (const float*)d_in[8];
  const float* wihf1 = (const float*)d_in[9];
  const float* whhf1 = (const float*)d_in[10];
  const float* bihf1 = (const float*)d_in[11];
  const float* bhhf1 = (const float*)d_in[12];
  const float* wihb1 = (const float*)d_in[13];
  const float* whhb1 = (const float*)d_in[14];
  const float* bihb1 = (const float*)d_in[15];
  const float* bhhb1 = (const float*)d_in[16];
  const float* fcw   = (const float*)d_in[17];
  const float* fcb   = (const float*)d_in[18];
  const float* mask  = (const float*)d_in[19];
  float* out = (float*)d_out;
  (void)in_sizes; (void)n_in; (void)out_size; (void)ws_size;

  char* w = (char*)d_ws;
  size_t off = 0;
  auto take = [&](size_t bytes) -> char* {
    char* p = w + off;
    off += (bytes + 255) & ~(size_t)255;
    return p;
  };
  unsigned* ctr = (unsigned*)take(16);
  u16* xbhi = (u16*)take((size_t)1024 * 64 * 256 * 2);   // 33.5 MB
  u16* xblo = (u16*)take((size_t)1024 * 64 * 256 * 2);
  u16* wxhiF0 = (u16*)take((size_t)2048 * 512 * 2);
  u16* wxloF0 = (u16*)take((size_t)2048 * 512 * 2);
  u16* wxhiB0 = (u16*)take((size_t)2048 * 512 * 2);
  u16* wxloB0 = (u16*)take((size_t)2048 * 512 * 2);
  u16* wxhiF1 = (u16*)take((size_t)2048 * 1024 * 2);
  u16* wxloF1 = (u16*)take((size_t)2048 * 1024 * 2);
  u16* wxhiB1 = (u16*)take((size_t)2048 * 1024 * 2);
  u16* wxloB1 = (u16*)take((size_t)2048 * 1024 * 2);
  u16* x1hi = (u16*)take((size_t)1024 * 128 * 256 * 2);  // 67 MB
  u16* x1lo = (u16*)take((size_t)1024 * 128 * 256 * 2);
  u16* hbuf = (u16*)take((size_t)2 * 65536 * 2);         // 256 KB
  float* hT = (float*)take((size_t)2 * 16384 * 4);       // 128 KB

  hipMemsetAsync(ctr, 0, 16, stream);

  k_xpose<<<8192, 256, 0, stream>>>(x, xbhi, xblo);
  k_wsplit<<<512, 256, 0, stream>>>(wihf0, wxhiF0, wxloF0);
  k_wsplit<<<512, 256, 0, stream>>>(wihb0, wxhiB0, wxloB0);
  k_wsplit<<<1024, 256, 0, stream>>>(wihf1, wxhiF1, wxloF1);
  k_wsplit<<<1024, 256, 0, stream>>>(wihb1, wxhiB1, wxloB1);

  // layer 0: fused input GEMM + recurrence (w_ih in registers)
  k_rec<64, true><<<64, 256, 0, stream>>>(
      xbhi, xblo, wxhiF0, wxloF0, wxhiB0, wxloB0, whhf0, whhb0, mask,
      bihf0, bhhf0, bihb0, bhhb0, x1hi, x1lo, nullptr, hbuf, ctr, 1024);
  // layer 1 (w_ih streamed from L2 — now stays warm)
  k_rec<128, false><<<64, 256, 0, stream>>>(
      x1hi, x1lo, wxhiF1, wxloF1, wxhiB1, wxloB1, whhf1, whhb1, nullptr,
      bihf1, bhhf1, bihb1, bhhb1, nullptr, nullptr, hT, hbuf, ctr + 2, 1024);

  k_head<<<dim3(32, 2), 256, 0, stream>>>(hT, fcw, fcb, out);
}